// Round 1
// baseline (830.611 us; speedup 1.0000x reference)
//
#include <hip/hip_runtime.h>

// GraphSAGE 2-layer encoder, MI355X (gfx950).
// Pipeline: cvt(x->bf16), cvt(weights->bf16 concat), CSR build (deg/scan/fill),
//   GEMM1: C1 = x @ [w1_l; w1_r]^T      (bf16 out, [Mpad,512])
//   agg1 : h = relu(mean(C1[:, :256][src]) + C1[:,256:] + b1) -> A2[:,256:]
//   agg2 : A2[:, :256] = mean(h[src])
//   GEMM2: out = A2 @ [w2_l | w2_r]^T + b2   (fp32 out)

#define IN_DIM  1024
#define HID_DIM 256
#define OUT_N   512

typedef __attribute__((ext_vector_type(8))) short bf16x8;
typedef __attribute__((ext_vector_type(4))) float f32x4;

static __device__ __forceinline__ unsigned short f2bf(float f) {
  unsigned int u = __float_as_uint(f);
  u += 0x7fffu + ((u >> 16) & 1u);           // round-to-nearest-even
  return (unsigned short)(u >> 16);
}
static __device__ __forceinline__ float bf2f(unsigned short b) {
  return __uint_as_float(((unsigned int)b) << 16);
}

// ---------- edge-index dtype probe: 1 if data looks like int64 ----------
__global__ void k_detect(const unsigned int* ei, int* flag) {
  unsigned int v = ei[2 * threadIdx.x + 1];
  unsigned long long m = __ballot(v == 0u);
  if (threadIdx.x == 0) *flag = (m == ~0ull) ? 1 : 0;
}

static __device__ __forceinline__ int load_idx(const void* ei, long long pos, int is64) {
  if (is64) return (int)((const long long*)ei)[pos];
  return ((const int*)ei)[pos];
}

// ---------- conversions ----------
__global__ void k_cvt_x(const float* __restrict__ x, unsigned short* __restrict__ xbf, int n4) {
  int i = blockIdx.x * 256 + threadIdx.x;
  if (i >= n4) return;
  float4 v = ((const float4*)x)[i];
  ushort4 o = { f2bf(v.x), f2bf(v.y), f2bf(v.z), f2bf(v.w) };
  ((ushort4*)xbf)[i] = o;
}

// W1cat[n][k], n in [0,512): n<256 -> w1_l[n][k], else w1_r[n-256][k]; K=1024
__global__ void k_cvt_w1(const float* __restrict__ wl, const float* __restrict__ wr,
                         unsigned short* __restrict__ out) {
  int i = blockIdx.x * 256 + threadIdx.x;         // group of 4 elems
  if (i >= 2 * HID_DIM * IN_DIM / 4) return;
  int base = i * 4;
  int n = base / IN_DIM, k = base % IN_DIM;
  const float* s = (n < HID_DIM) ? &wl[(size_t)n * IN_DIM + k]
                                 : &wr[(size_t)(n - HID_DIM) * IN_DIM + k];
  float4 v = *(const float4*)s;
  ushort4 o = { f2bf(v.x), f2bf(v.y), f2bf(v.z), f2bf(v.w) };
  *(ushort4*)&out[base] = o;
}

// W2cat[n][k], n in [0,512), k in [0,512): k<256 -> w2_l[n][k], else w2_r[n][k-256]
__global__ void k_cvt_w2(const float* __restrict__ wl, const float* __restrict__ wr,
                         unsigned short* __restrict__ out) {
  int i = blockIdx.x * 256 + threadIdx.x;
  if (i >= OUT_N * 2 * HID_DIM / 4) return;
  int base = i * 4;
  int n = base >> 9, k = base & 511;
  const float* s = (k < HID_DIM) ? &wl[(size_t)n * HID_DIM + k]
                                 : &wr[(size_t)n * HID_DIM + (k - HID_DIM)];
  float4 v = *(const float4*)s;
  ushort4 o = { f2bf(v.x), f2bf(v.y), f2bf(v.z), f2bf(v.w) };
  *(ushort4*)&out[base] = o;
}

// ---------- CSR build ----------
__global__ void k_deg(const void* ei, int nE, const int* flag, int* deg) {
  int e = blockIdx.x * 256 + threadIdx.x;
  if (e >= nE) return;
  int d = load_idx(ei, (long long)nE + e, *flag);
  atomicAdd(&deg[d], 1);
}

__global__ __launch_bounds__(1024) void k_scan(const int* __restrict__ deg,
                                               int* __restrict__ off, int n) {
  __shared__ int sums[1024];
  int t = threadIdx.x;
  int chunk = (n + 1023) >> 10;
  int base = t * chunk;
  int s = 0;
  for (int i = 0; i < chunk; ++i) { int idx = base + i; if (idx < n) s += deg[idx]; }
  sums[t] = s;
  __syncthreads();
  for (int d = 1; d < 1024; d <<= 1) {
    int v = 0;
    if (t >= d) v = sums[t - d];
    __syncthreads();
    sums[t] += v;
    __syncthreads();
  }
  int run = (t == 0) ? 0 : sums[t - 1];
  for (int i = 0; i < chunk; ++i) {
    int idx = base + i;
    if (idx < n) { off[idx] = run; run += deg[idx]; }
  }
  if (t == 1023) off[n] = run;
}

__global__ void k_fill(const void* ei, int nE, const int* flag,
                       const int* __restrict__ off, int* cursor, int* __restrict__ csr) {
  int e = blockIdx.x * 256 + threadIdx.x;
  if (e >= nE) return;
  int is64 = *flag;
  int s = load_idx(ei, e, is64);
  int d = load_idx(ei, (long long)nE + e, is64);
  int p = atomicAdd(&cursor[d], 1);
  csr[off[d] + p] = s;
}

// ---------- GEMM: C[M,N] = A[M,K](bf16) @ B[N,K](bf16)^T  (m97-style) ----------
// 128x128 tile, BK=32, 4 waves in 2x2, each wave 64x64 via 4x4 mfma_f32_16x16x32_bf16.
static __device__ __forceinline__ void load_lds16(const void* g, void* lds) {
  __builtin_amdgcn_global_load_lds(
      (const __attribute__((address_space(1))) unsigned int*)g,
      (__attribute__((address_space(3))) unsigned int*)lds, 16, 0, 0);
}

template <bool BF16OUT, bool GUARD, bool BIAS>
__global__ __launch_bounds__(256) void k_gemm(const unsigned short* __restrict__ A,
                                              const unsigned short* __restrict__ B,
                                              void* __restrict__ Cout, int K, int N,
                                              const float* __restrict__ bias, int Mstore) {
  __shared__ unsigned short As[128 * 32];
  __shared__ unsigned short Bs[128 * 32];
  const int tid = threadIdx.x;
  const int w = tid >> 6, l = tid & 63;
  const int wm = w >> 1, wn = w & 1;
  const int quad = l >> 4, lane16 = l & 15;
  const int m0 = blockIdx.y * 128;
  const int n0 = blockIdx.x * 128;

  f32x4 acc[4][4] = {};

  for (int k0 = 0; k0 < K; k0 += 32) {
#pragma unroll
    for (int c = 0; c < 2; ++c) {
      const int flat = ((w * 2 + c) << 10);          // byte base of this wave-call
      const int fb = flat + l * 16;
      const int row = fb >> 6;                        // 64 B per tile row
      const int cb = fb & 63;
      const unsigned short* ga = A + (size_t)(m0 + row) * K + (k0 + (cb >> 1));
      load_lds16(ga, (char*)As + flat);
      const unsigned short* gb = B + (size_t)(n0 + row) * K + (k0 + (cb >> 1));
      load_lds16(gb, (char*)Bs + flat);
    }
    __syncthreads();

    bf16x8 af[4], bfr[4];
#pragma unroll
    for (int i = 0; i < 4; ++i)
      af[i] = *(const bf16x8*)&As[(wm * 64 + i * 16 + lane16) * 32 + quad * 8];
#pragma unroll
    for (int j = 0; j < 4; ++j)
      bfr[j] = *(const bf16x8*)&Bs[(wn * 64 + j * 16 + lane16) * 32 + quad * 8];
#pragma unroll
    for (int i = 0; i < 4; ++i)
#pragma unroll
      for (int j = 0; j < 4; ++j)
        acc[i][j] = __builtin_amdgcn_mfma_f32_16x16x32_bf16(af[i], bfr[j], acc[i][j], 0, 0, 0);
    __syncthreads();
  }

  // epilogue: D row = quad*4 + r, col = lane16   [measured m89/m91 layout]
#pragma unroll
  for (int i = 0; i < 4; ++i) {
    const int rbase = m0 + wm * 64 + i * 16 + quad * 4;
#pragma unroll
    for (int j = 0; j < 4; ++j) {
      const int col = n0 + wn * 64 + j * 16 + lane16;
      const float bv = BIAS ? bias[col] : 0.0f;
#pragma unroll
      for (int r = 0; r < 4; ++r) {
        const int rowi = rbase + r;
        if (!GUARD || rowi < Mstore) {
          float v = acc[i][j][r] + bv;
          if (BF16OUT)
            ((unsigned short*)Cout)[(size_t)rowi * N + col] = f2bf(v);
          else
            ((float*)Cout)[(size_t)rowi * N + col] = v;
        }
      }
    }
  }
}

// ---------- aggregations (1 wave per node, lane covers 4 columns) ----------
// agg1: A2[node][256+c] = bf16(relu(mean(C1[src][c]) + C1[node][256+c] + b1[c]))
__global__ void k_agg1(const unsigned short* __restrict__ C1, const int* __restrict__ off,
                       const int* __restrict__ csr, const float* __restrict__ b1,
                       unsigned short* __restrict__ A2, int nNodes) {
  int node = blockIdx.x * 4 + (threadIdx.x >> 6);
  int l = threadIdx.x & 63;
  if (node >= nNodes) return;
  int s = off[node], e = off[node + 1];
  float a0 = 0.f, a1 = 0.f, a2 = 0.f, a3 = 0.f;
  for (int i = s; i < e; ++i) {
    int src = csr[i];
    ushort4 v = *(const ushort4*)&C1[(size_t)src * 512 + l * 4];
    a0 += bf2f(v.x); a1 += bf2f(v.y); a2 += bf2f(v.z); a3 += bf2f(v.w);
  }
  float inv = 1.0f / fmaxf((float)(e - s), 1.0f);
  ushort4 xr = *(const ushort4*)&C1[(size_t)node * 512 + 256 + l * 4];
  float4 bb = *(const float4*)&b1[l * 4];
  float h0 = fmaxf(a0 * inv + bf2f(xr.x) + bb.x, 0.0f);
  float h1 = fmaxf(a1 * inv + bf2f(xr.y) + bb.y, 0.0f);
  float h2 = fmaxf(a2 * inv + bf2f(xr.z) + bb.z, 0.0f);
  float h3 = fmaxf(a3 * inv + bf2f(xr.w) + bb.w, 0.0f);
  ushort4 o = { f2bf(h0), f2bf(h1), f2bf(h2), f2bf(h3) };
  *(ushort4*)&A2[(size_t)node * 512 + 256 + l * 4] = o;
}

// agg2: A2[node][c] = bf16(mean(A2[src][256+c]))   (reads h half, writes mean half)
__global__ void k_agg2(const int* __restrict__ off, const int* __restrict__ csr,
                       unsigned short* __restrict__ A2, int nNodes) {
  int node = blockIdx.x * 4 + (threadIdx.x >> 6);
  int l = threadIdx.x & 63;
  if (node >= nNodes) return;
  int s = off[node], e = off[node + 1];
  float a0 = 0.f, a1 = 0.f, a2 = 0.f, a3 = 0.f;
  for (int i = s; i < e; ++i) {
    int src = csr[i];
    ushort4 v = *(const ushort4*)&A2[(size_t)src * 512 + 256 + l * 4];
    a0 += bf2f(v.x); a1 += bf2f(v.y); a2 += bf2f(v.z); a3 += bf2f(v.w);
  }
  float inv = 1.0f / fmaxf((float)(e - s), 1.0f);
  ushort4 o = { f2bf(a0 * inv), f2bf(a1 * inv), f2bf(a2 * inv), f2bf(a3 * inv) };
  *(ushort4*)&A2[(size_t)node * 512 + l * 4] = o;
}

extern "C" void kernel_launch(void* const* d_in, const int* in_sizes, int n_in,
                              void* d_out, int out_size, void* d_ws, size_t ws_size,
                              hipStream_t stream) {
  const float* x   = (const float*)d_in[0];
  const void*  ei  = d_in[1];
  const float* w1l = (const float*)d_in[2];
  const float* w1r = (const float*)d_in[3];
  const float* b1  = (const float*)d_in[4];
  const float* w2l = (const float*)d_in[5];
  const float* w2r = (const float*)d_in[6];
  const float* b2  = (const float*)d_in[7];
  float* out = (float*)d_out;

  const int nN   = in_sizes[0] / IN_DIM;         // 50000
  const int nE   = in_sizes[1] / 2;              // 800000
  const int Mpad = (nN + 127) & ~127;            // 50048

  char* ws = (char*)d_ws;
  size_t o = 0;
  auto alloc = [&](size_t bytes) {
    char* p = ws + o;
    o += (bytes + 255) & ~(size_t)255;
    return p;
  };
  unsigned short* xbf = (unsigned short*)alloc((size_t)Mpad * IN_DIM * 2);     // 102.5 MB
  unsigned short* W1c = (unsigned short*)alloc((size_t)2 * HID_DIM * IN_DIM * 2);
  unsigned short* W2c = (unsigned short*)alloc((size_t)OUT_N * 2 * HID_DIM * 2);
  unsigned short* C1  = (unsigned short*)alloc((size_t)Mpad * 512 * 2);        // 51.2 MB
  unsigned short* A2  = (unsigned short*)alloc((size_t)Mpad * 512 * 2);        // 51.2 MB
  int* deg    = (int*)alloc((size_t)nN * 4);
  int* offs   = (int*)alloc((size_t)(nN + 1) * 4);
  int* cursor = (int*)alloc((size_t)nN * 4);
  int* csr    = (int*)alloc((size_t)nE * 4);
  int* flag   = (int*)alloc(256);

  hipMemsetAsync(deg, 0, (size_t)nN * 4, stream);
  hipMemsetAsync(cursor, 0, (size_t)nN * 4, stream);
  hipMemsetAsync(xbf + (size_t)nN * IN_DIM, 0, (size_t)(Mpad - nN) * IN_DIM * 2, stream);
  hipMemsetAsync(A2 + (size_t)nN * 512, 0, (size_t)(Mpad - nN) * 512 * 2, stream);

  k_detect<<<1, 64, 0, stream>>>((const unsigned int*)ei, flag);
  k_cvt_x<<<(nN * IN_DIM / 4 + 255) / 256, 256, 0, stream>>>(x, xbf, nN * IN_DIM / 4);
  k_cvt_w1<<<(2 * HID_DIM * IN_DIM / 4 + 255) / 256, 256, 0, stream>>>(w1l, w1r, W1c);
  k_cvt_w2<<<(OUT_N * 2 * HID_DIM / 4 + 255) / 256, 256, 0, stream>>>(w2l, w2r, W2c);
  k_deg<<<(nE + 255) / 256, 256, 0, stream>>>(ei, nE, flag, deg);
  k_scan<<<1, 1024, 0, stream>>>(deg, offs, nN);
  k_fill<<<(nE + 255) / 256, 256, 0, stream>>>(ei, nE, flag, offs, cursor, csr);

  dim3 gemmGrid(512 / 128, Mpad / 128);
  // GEMM1: C1 = xbf @ W1cat^T (bf16 out, no guard: pad rows are zeroed input)
  k_gemm<true, false, false><<<gemmGrid, 256, 0, stream>>>(xbf, W1c, C1, IN_DIM, 512, nullptr, 0);
  k_agg1<<<(nN + 3) / 4, 256, 0, stream>>>(C1, offs, csr, b1, A2, nN);
  k_agg2<<<(nN + 3) / 4, 256, 0, stream>>>(offs, csr, A2, nN);
  // GEMM2: out = A2 @ W2cat^T + b2 (fp32 out, guard rows < nN)
  k_gemm<false, true, true><<<gemmGrid, 256, 0, stream>>>(A2, W2c, out, 2 * HID_DIM, 512, b2, nN);
}

// Round 2
// 753.844 us; speedup vs baseline: 1.1018x; 1.1018x over previous
//
#include <hip/hip_runtime.h>

// GraphSAGE 2-layer encoder, MI355X (gfx950).  Round 2.
// Split gather buffers + 4-edge-batched gathers + fused misc kernels.
//   GEMM1: Cl = x@w1_l^T ; Cr = x@w1_r^T + b1          (bf16, [Mpad,256] each)
//   agg1 : h[n] = relu(mean(Cl[src]) + Cr[n])          (bf16 [Mpad,256])
//   agg2 : mean2[n] = mean(h[src])                     (bf16 [Mpad,256])
//   GEMM2: out = [mean2|h] @ [w2_l|w2_r]^T + b2        (fp32 [nN,512])

#define IN_DIM  1024
#define HID_DIM 256
#define OUT_N   512

typedef __attribute__((ext_vector_type(8))) short bf16x8;
typedef __attribute__((ext_vector_type(4))) float f32x4;

static __device__ __forceinline__ unsigned short f2bf(float f) {
  unsigned int u = __float_as_uint(f);
  u += 0x7fffu + ((u >> 16) & 1u);
  return (unsigned short)(u >> 16);
}
static __device__ __forceinline__ float bf2f(unsigned short b) {
  return __uint_as_float(((unsigned int)b) << 16);
}

static __device__ __forceinline__ int load_idx(const void* ei, long long pos, int is64) {
  if (is64) return (int)((const long long*)ei)[pos];
  return ((const int*)ei)[pos];
}

// ---------- fused: edge-dtype detect + weight conversions ----------
// block 0: detect; blocks [1, 1+512): w1cat; blocks [1+512, 1+512+256): w2cat
__global__ void k_misc(const unsigned int* __restrict__ ei, int* __restrict__ flag,
                       const float* __restrict__ w1l, const float* __restrict__ w1r,
                       unsigned short* __restrict__ W1c,
                       const float* __restrict__ w2l, const float* __restrict__ w2r,
                       unsigned short* __restrict__ W2c) {
  int b = blockIdx.x;
  if (b == 0) {
    if (threadIdx.x < 64) {
      unsigned int v = ei[2 * threadIdx.x + 1];
      unsigned long long m = __ballot(v == 0u);
      if (threadIdx.x == 0) *flag = (m == ~0ull) ? 1 : 0;
    }
    return;
  }
  b -= 1;
  if (b < 512) {                      // W1cat[n][k], n<256 -> w1_l else w1_r; K=1024
    int i = b * 256 + threadIdx.x;
    int base = i * 4;
    int n = base / IN_DIM, k = base % IN_DIM;
    const float* s = (n < HID_DIM) ? &w1l[(size_t)n * IN_DIM + k]
                                   : &w1r[(size_t)(n - HID_DIM) * IN_DIM + k];
    float4 v = *(const float4*)s;
    ushort4 o = { f2bf(v.x), f2bf(v.y), f2bf(v.z), f2bf(v.w) };
    *(ushort4*)&W1c[base] = o;
  } else {                            // W2cat[n][k], k<256 -> w2_l else w2_r; K=512
    int i = (b - 512) * 256 + threadIdx.x;
    int base = i * 4;
    int n = base >> 9, k = base & 511;
    const float* s = (k < HID_DIM) ? &w2l[(size_t)n * HID_DIM + k]
                                   : &w2r[(size_t)n * HID_DIM + (k - HID_DIM)];
    float4 v = *(const float4*)s;
    ushort4 o = { f2bf(v.x), f2bf(v.y), f2bf(v.z), f2bf(v.w) };
    *(ushort4*)&W2c[base] = o;
  }
}

__global__ void k_cvt_x(const float* __restrict__ x, unsigned short* __restrict__ xbf, int n4) {
  int i = blockIdx.x * 256 + threadIdx.x;
  if (i >= n4) return;
  float4 v = ((const float4*)x)[i];
  ushort4 o = { f2bf(v.x), f2bf(v.y), f2bf(v.z), f2bf(v.w) };
  ((ushort4*)xbf)[i] = o;
}

// ---------- CSR build ----------
__global__ void k_deg(const void* ei, int nE, const int* flag, int* deg) {
  int e = blockIdx.x * 256 + threadIdx.x;
  if (e >= nE) return;
  int d = load_idx(ei, (long long)nE + e, *flag);
  atomicAdd(&deg[d], 1);
}

__global__ __launch_bounds__(1024) void k_scan(const int* __restrict__ deg,
                                               int* __restrict__ off, int n) {
  __shared__ int sums[1024];
  int t = threadIdx.x;
  int chunk = (n + 1023) >> 10;
  int base = t * chunk;
  int s = 0;
  for (int i = 0; i < chunk; ++i) { int idx = base + i; if (idx < n) s += deg[idx]; }
  sums[t] = s;
  __syncthreads();
  for (int d = 1; d < 1024; d <<= 1) {
    int v = 0;
    if (t >= d) v = sums[t - d];
    __syncthreads();
    sums[t] += v;
    __syncthreads();
  }
  int run = (t == 0) ? 0 : sums[t - 1];
  for (int i = 0; i < chunk; ++i) {
    int idx = base + i;
    if (idx < n) { off[idx] = run; run += deg[idx]; }
  }
  if (t == 1023) off[n] = run;
}

__global__ void k_fill(const void* ei, int nE, const int* flag,
                       const int* __restrict__ off, int* cursor, int* __restrict__ csr) {
  int e = blockIdx.x * 256 + threadIdx.x;
  if (e >= nE) return;
  int is64 = *flag;
  int s = load_idx(ei, e, is64);
  int d = load_idx(ei, (long long)nE + e, is64);
  int p = atomicAdd(&cursor[d], 1);
  csr[off[d] + p] = s;
}

// ---------- GEMMs (m97-style: 128x128 tile, BK=32, 4 waves 2x2, 4x4 mfma) ----------
static __device__ __forceinline__ void load_lds16(const void* g, void* lds) {
  __builtin_amdgcn_global_load_lds(
      (const __attribute__((address_space(1))) unsigned int*)g,
      (__attribute__((address_space(3))) unsigned int*)lds, 16, 0, 0);
}

// GEMM1: A=[Mpad,1024] bf16, B=W1c[512,1024] bf16; out split Cl/Cr (+b1 on right)
__global__ __launch_bounds__(256) void k_gemm1(const unsigned short* __restrict__ A,
                                               const unsigned short* __restrict__ B,
                                               unsigned short* __restrict__ Cl,
                                               unsigned short* __restrict__ Cr,
                                               const float* __restrict__ b1) {
  __shared__ unsigned short As[128 * 32];
  __shared__ unsigned short Bs[128 * 32];
  const int tid = threadIdx.x;
  const int w = tid >> 6, l = tid & 63;
  const int wm = w >> 1, wn = w & 1;
  const int quad = l >> 4, lane16 = l & 15;
  const int m0 = blockIdx.y * 128;
  const int n0 = blockIdx.x * 128;

  f32x4 acc[4][4] = {};
  for (int k0 = 0; k0 < IN_DIM; k0 += 32) {
#pragma unroll
    for (int c = 0; c < 2; ++c) {
      const int flat = ((w * 2 + c) << 10);
      const int fb = flat + l * 16;
      const int row = fb >> 6;
      const int cb = fb & 63;
      load_lds16(A + (size_t)(m0 + row) * IN_DIM + (k0 + (cb >> 1)), (char*)As + flat);
      load_lds16(B + (size_t)(n0 + row) * IN_DIM + (k0 + (cb >> 1)), (char*)Bs + flat);
    }
    __syncthreads();
    bf16x8 af[4], bfr[4];
#pragma unroll
    for (int i = 0; i < 4; ++i)
      af[i] = *(const bf16x8*)&As[(wm * 64 + i * 16 + lane16) * 32 + quad * 8];
#pragma unroll
    for (int j = 0; j < 4; ++j)
      bfr[j] = *(const bf16x8*)&Bs[(wn * 64 + j * 16 + lane16) * 32 + quad * 8];
#pragma unroll
    for (int i = 0; i < 4; ++i)
#pragma unroll
      for (int j = 0; j < 4; ++j)
        acc[i][j] = __builtin_amdgcn_mfma_f32_16x16x32_bf16(af[i], bfr[j], acc[i][j], 0, 0, 0);
    __syncthreads();
  }

  const bool right = (n0 >= 256);
  unsigned short* Cb = right ? Cr : Cl;
  const int nc0 = n0 - (right ? 256 : 0);
#pragma unroll
  for (int i = 0; i < 4; ++i) {
    const int rbase = m0 + wm * 64 + i * 16 + quad * 4;
#pragma unroll
    for (int j = 0; j < 4; ++j) {
      const int col = nc0 + wn * 64 + j * 16 + lane16;
      const float bv = right ? b1[col] : 0.0f;
#pragma unroll
      for (int r = 0; r < 4; ++r)
        Cb[(size_t)(rbase + r) * HID_DIM + col] = f2bf(acc[i][j][r] + bv);
    }
  }
}

// GEMM2: A k<256 from Am (mean2), k>=256 from Ah (h); B=W2c[512,512]; fp32 out + b2
__global__ __launch_bounds__(256) void k_gemm2(const unsigned short* __restrict__ Am,
                                               const unsigned short* __restrict__ Ah,
                                               const unsigned short* __restrict__ B,
                                               float* __restrict__ out,
                                               const float* __restrict__ b2, int Mstore) {
  __shared__ unsigned short As[128 * 32];
  __shared__ unsigned short Bs[128 * 32];
  const int tid = threadIdx.x;
  const int w = tid >> 6, l = tid & 63;
  const int wm = w >> 1, wn = w & 1;
  const int quad = l >> 4, lane16 = l & 15;
  const int m0 = blockIdx.y * 128;
  const int n0 = blockIdx.x * 128;

  f32x4 acc[4][4] = {};
  for (int k0 = 0; k0 < 2 * HID_DIM; k0 += 32) {
    const unsigned short* Abase = (k0 < HID_DIM) ? Am + k0 : Ah + (k0 - HID_DIM);
#pragma unroll
    for (int c = 0; c < 2; ++c) {
      const int flat = ((w * 2 + c) << 10);
      const int fb = flat + l * 16;
      const int row = fb >> 6;
      const int cb = fb & 63;
      load_lds16(Abase + (size_t)(m0 + row) * HID_DIM + (cb >> 1), (char*)As + flat);
      load_lds16(B + (size_t)(n0 + row) * (2 * HID_DIM) + (k0 + (cb >> 1)), (char*)Bs + flat);
    }
    __syncthreads();
    bf16x8 af[4], bfr[4];
#pragma unroll
    for (int i = 0; i < 4; ++i)
      af[i] = *(const bf16x8*)&As[(wm * 64 + i * 16 + lane16) * 32 + quad * 8];
#pragma unroll
    for (int j = 0; j < 4; ++j)
      bfr[j] = *(const bf16x8*)&Bs[(wn * 64 + j * 16 + lane16) * 32 + quad * 8];
#pragma unroll
    for (int i = 0; i < 4; ++i)
#pragma unroll
      for (int j = 0; j < 4; ++j)
        acc[i][j] = __builtin_amdgcn_mfma_f32_16x16x32_bf16(af[i], bfr[j], acc[i][j], 0, 0, 0);
    __syncthreads();
  }

#pragma unroll
  for (int i = 0; i < 4; ++i) {
    const int rbase = m0 + wm * 64 + i * 16 + quad * 4;
#pragma unroll
    for (int j = 0; j < 4; ++j) {
      const int col = n0 + wn * 64 + j * 16 + lane16;
      const float bv = b2[col];
#pragma unroll
      for (int r = 0; r < 4; ++r) {
        const int rowi = rbase + r;
        if (rowi < Mstore) out[(size_t)rowi * OUT_N + col] = acc[i][j][r] + bv;
      }
    }
  }
}

// ---------- aggregations: 1 wave/node, lane=4 cols, 4-edge batched gather ----------
__global__ void k_agg1(const unsigned short* __restrict__ Cl,
                       const unsigned short* __restrict__ Cr,
                       const int* __restrict__ off, const int* __restrict__ csr,
                       unsigned short* __restrict__ h, int nNodes) {
  int node = blockIdx.x * 4 + (threadIdx.x >> 6);
  int l = threadIdx.x & 63;
  if (node >= nNodes) return;
  int s = off[node], e = off[node + 1];
  float a0 = 0.f, a1 = 0.f, a2 = 0.f, a3 = 0.f;
  int i = s;
  for (; i + 4 <= e; i += 4) {
    int s0 = csr[i], s1 = csr[i + 1], s2 = csr[i + 2], s3 = csr[i + 3];
    ushort4 v0 = *(const ushort4*)&Cl[(size_t)s0 * HID_DIM + l * 4];
    ushort4 v1 = *(const ushort4*)&Cl[(size_t)s1 * HID_DIM + l * 4];
    ushort4 v2 = *(const ushort4*)&Cl[(size_t)s2 * HID_DIM + l * 4];
    ushort4 v3 = *(const ushort4*)&Cl[(size_t)s3 * HID_DIM + l * 4];
    a0 += bf2f(v0.x) + bf2f(v1.x) + bf2f(v2.x) + bf2f(v3.x);
    a1 += bf2f(v0.y) + bf2f(v1.y) + bf2f(v2.y) + bf2f(v3.y);
    a2 += bf2f(v0.z) + bf2f(v1.z) + bf2f(v2.z) + bf2f(v3.z);
    a3 += bf2f(v0.w) + bf2f(v1.w) + bf2f(v2.w) + bf2f(v3.w);
  }
  for (; i < e; ++i) {
    int s0 = csr[i];
    ushort4 v = *(const ushort4*)&Cl[(size_t)s0 * HID_DIM + l * 4];
    a0 += bf2f(v.x); a1 += bf2f(v.y); a2 += bf2f(v.z); a3 += bf2f(v.w);
  }
  float inv = 1.0f / fmaxf((float)(e - s), 1.0f);
  ushort4 xr = *(const ushort4*)&Cr[(size_t)node * HID_DIM + l * 4];   // includes b1
  ushort4 o = { f2bf(fmaxf(a0 * inv + bf2f(xr.x), 0.0f)),
                f2bf(fmaxf(a1 * inv + bf2f(xr.y), 0.0f)),
                f2bf(fmaxf(a2 * inv + bf2f(xr.z), 0.0f)),
                f2bf(fmaxf(a3 * inv + bf2f(xr.w), 0.0f)) };
  *(ushort4*)&h[(size_t)node * HID_DIM + l * 4] = o;
}

__global__ void k_agg2(const unsigned short* __restrict__ h,
                       const int* __restrict__ off, const int* __restrict__ csr,
                       unsigned short* __restrict__ mean2, int nNodes) {
  int node = blockIdx.x * 4 + (threadIdx.x >> 6);
  int l = threadIdx.x & 63;
  if (node >= nNodes) return;
  int s = off[node], e = off[node + 1];
  float a0 = 0.f, a1 = 0.f, a2 = 0.f, a3 = 0.f;
  int i = s;
  for (; i + 4 <= e; i += 4) {
    int s0 = csr[i], s1 = csr[i + 1], s2 = csr[i + 2], s3 = csr[i + 3];
    ushort4 v0 = *(const ushort4*)&h[(size_t)s0 * HID_DIM + l * 4];
    ushort4 v1 = *(const ushort4*)&h[(size_t)s1 * HID_DIM + l * 4];
    ushort4 v2 = *(const ushort4*)&h[(size_t)s2 * HID_DIM + l * 4];
    ushort4 v3 = *(const ushort4*)&h[(size_t)s3 * HID_DIM + l * 4];
    a0 += bf2f(v0.x) + bf2f(v1.x) + bf2f(v2.x) + bf2f(v3.x);
    a1 += bf2f(v0.y) + bf2f(v1.y) + bf2f(v2.y) + bf2f(v3.y);
    a2 += bf2f(v0.z) + bf2f(v1.z) + bf2f(v2.z) + bf2f(v3.z);
    a3 += bf2f(v0.w) + bf2f(v1.w) + bf2f(v2.w) + bf2f(v3.w);
  }
  for (; i < e; ++i) {
    int s0 = csr[i];
    ushort4 v = *(const ushort4*)&h[(size_t)s0 * HID_DIM + l * 4];
    a0 += bf2f(v.x); a1 += bf2f(v.y); a2 += bf2f(v.z); a3 += bf2f(v.w);
  }
  float inv = 1.0f / fmaxf((float)(e - s), 1.0f);
  ushort4 o = { f2bf(a0 * inv), f2bf(a1 * inv), f2bf(a2 * inv), f2bf(a3 * inv) };
  *(ushort4*)&mean2[(size_t)node * HID_DIM + l * 4] = o;
}

extern "C" void kernel_launch(void* const* d_in, const int* in_sizes, int n_in,
                              void* d_out, int out_size, void* d_ws, size_t ws_size,
                              hipStream_t stream) {
  const float* x   = (const float*)d_in[0];
  const void*  ei  = d_in[1];
  const float* w1l = (const float*)d_in[2];
  const float* w1r = (const float*)d_in[3];
  const float* b1  = (const float*)d_in[4];
  const float* w2l = (const float*)d_in[5];
  const float* w2r = (const float*)d_in[6];
  const float* b2  = (const float*)d_in[7];
  float* out = (float*)d_out;

  const int nN   = in_sizes[0] / IN_DIM;         // 50000
  const int nE   = in_sizes[1] / 2;              // 800000
  const int Mpad = (nN + 127) & ~127;            // 50048

  char* ws = (char*)d_ws;
  size_t o = 0;
  auto alloc = [&](size_t bytes) {
    char* p = ws + o;
    o += (bytes + 255) & ~(size_t)255;
    return p;
  };
  unsigned short* xbf   = (unsigned short*)alloc((size_t)Mpad * IN_DIM * 2);
  unsigned short* W1c   = (unsigned short*)alloc((size_t)2 * HID_DIM * IN_DIM * 2);
  unsigned short* W2c   = (unsigned short*)alloc((size_t)OUT_N * 2 * HID_DIM * 2);
  unsigned short* Cl    = (unsigned short*)alloc((size_t)Mpad * HID_DIM * 2);
  unsigned short* Cr    = (unsigned short*)alloc((size_t)Mpad * HID_DIM * 2);
  unsigned short* hbuf  = (unsigned short*)alloc((size_t)Mpad * HID_DIM * 2);
  unsigned short* mean2 = (unsigned short*)alloc((size_t)Mpad * HID_DIM * 2);
  int* deg    = (int*)alloc((size_t)nN * 4);
  int* offs   = (int*)alloc((size_t)(nN + 1) * 4);
  int* cursor = (int*)alloc((size_t)nN * 4);
  int* csr    = (int*)alloc((size_t)nE * 4);
  int* flag   = (int*)alloc(256);

  hipMemsetAsync(deg, 0, (size_t)nN * 4, stream);
  hipMemsetAsync(cursor, 0, (size_t)nN * 4, stream);
  // pad rows of xbf / hbuf / mean2 stay 0xAA poison: decodes to ~1e-13 bf16,
  // flows only into pad rows of Cl/Cr/out-guarded stores -> never observed.

  k_misc<<<1 + 512 + 256, 256, 0, stream>>>((const unsigned int*)ei, flag,
                                            w1l, w1r, W1c, w2l, w2r, W2c);
  k_cvt_x<<<(nN * IN_DIM / 4 + 255) / 256, 256, 0, stream>>>(x, xbf, nN * IN_DIM / 4);
  k_deg<<<(nE + 255) / 256, 256, 0, stream>>>(ei, nE, flag, deg);
  k_scan<<<1, 1024, 0, stream>>>(deg, offs, nN);
  k_fill<<<(nE + 255) / 256, 256, 0, stream>>>(ei, nE, flag, offs, cursor, csr);

  dim3 g1(512 / 128, Mpad / 128);
  k_gemm1<<<g1, 256, 0, stream>>>(xbf, W1c, Cl, Cr, b1);
  k_agg1<<<(nN + 3) / 4, 256, 0, stream>>>(Cl, Cr, offs, csr, hbuf, nN);
  k_agg2<<<(nN + 3) / 4, 256, 0, stream>>>(hbuf, offs, csr, mean2, nN);
  k_gemm2<<<g1, 256, 0, stream>>>(mean2, hbuf, W2c, out, b2, nN);
}